// Round 5
// baseline (181.634 us; speedup 1.0000x reference)
//
#include <hip/hip_runtime.h>

#define C 128
#define HID 256
#define MT 64     // nodes per block in mlp_mfma
#define EPB 4096  // edges per block in bucket passes
#define BSH 8     // nodes per bucket = 256

typedef __attribute__((ext_vector_type(8))) short bf16x8;
typedef __attribute__((ext_vector_type(4))) short s16x4;
typedef __attribute__((ext_vector_type(4))) float f32x4;

__device__ inline unsigned short f2b(float f) {
    unsigned u = __builtin_bit_cast(unsigned, f);
    unsigned r = u + 0x7fffu + ((u >> 16) & 1u);
    return (unsigned short)(r >> 16);
}

// ---------- x -> bf16 copy ----------

__global__ __launch_bounds__(256) void convert_x(
    const float* __restrict__ x, unsigned short* __restrict__ xb, long total4)
{
    long i = (long)blockIdx.x * 256 + threadIdx.x;
    if (i < total4) {
        float4 v = *(const float4*)(x + i * 4);
        ushort4 o;
        o.x = f2b(v.x); o.y = f2b(v.y); o.z = f2b(v.z); o.w = f2b(v.w);
        *(ushort4*)(xb + i * 4) = o;
    }
}

// ---------- weight convert + permute into MFMA B-fragment order ----------
// lane l, elem j holds B[k][n]: n = nt*16+(l&15), k = kk*32+16*(j>>2)+4*(l>>4)+(j&3)

__global__ __launch_bounds__(256) void convert_w(
    const float* __restrict__ W1, const float* __restrict__ W2,
    unsigned short* __restrict__ W1p, unsigned short* __restrict__ W2p)
{
    int t = blockIdx.x * 256 + threadIdx.x;
    if (t < C * HID) {
        {
            int j = t & 7, l = (t >> 3) & 63, kk = (t >> 9) & 3, nt = t >> 11;
            int n = nt * 16 + (l & 15);
            int k = kk * 32 + 16 * (j >> 2) + 4 * (l >> 4) + (j & 3);
            W1p[t] = f2b(W1[k * HID + n]);
        }
        {
            int j = t & 7, l = (t >> 3) & 63, kk = (t >> 9) & 7, nt = t >> 12;
            int n = nt * 16 + (l & 15);
            int k = kk * 32 + 16 * (j >> 2) + 4 * (l >> 4) + (j & 3);
            W2p[t] = f2b(W2[k * C + n]);
        }
    }
}

// ---------- bucket sort pass 1: per-block histogram over buckets ----------

__global__ __launch_bounds__(256) void bucket_count(
    const int* __restrict__ ei, int* __restrict__ counts, int E, int NB, int NBLK)
{
    __shared__ int bins[256];   // NB <= 256 (N <= 65536)
    const int t = threadIdx.x;
    bins[t] = 0;
    __syncthreads();
    const int base = blockIdx.x * EPB;
    const int end  = min(base + EPB, E);
    for (int e = base + t; e < end; e += 256)
        atomicAdd(&bins[ei[E + e] >> BSH], 1);
    __syncthreads();
    if (t < NB) counts[t * NBLK + blockIdx.x] = bins[t];
}

// ---------- pass 2: bases + bucket starts (single block) ----------

__global__ __launch_bounds__(256) void bucket_scan(
    int* __restrict__ counts /* in: counts, out: bases */,
    int* __restrict__ bucket_start, int NB, int NBLK)
{
    __shared__ int s[256];
    const int t = threadIdx.x;
    int tot = 0;
    if (t < NB)
        for (int i = 0; i < NBLK; ++i) tot += counts[t * NBLK + i];
    s[t] = tot;
    __syncthreads();
    for (int off = 1; off < 256; off <<= 1) {
        int v = (t >= off) ? s[t - off] : 0;
        __syncthreads();
        s[t] += v;
        __syncthreads();
    }
    const int start = s[t] - tot;   // exclusive
    if (t < NB) {
        int run = start;
        for (int i = 0; i < NBLK; ++i) {
            int c = counts[t * NBLK + i];
            counts[t * NBLK + i] = run;
            run += c;
        }
        bucket_start[t] = start;
        if (t == NB - 1) bucket_start[NB] = run;
    }
}

// ---------- pass 3: scatter edges into bucket-partitioned tmp ----------

__global__ __launch_bounds__(256) void bucket_scatter(
    const int* __restrict__ ei, const float* __restrict__ ea,
    const int* __restrict__ bases, uint2* __restrict__ tmp,
    int E, int NB, int NBLK)
{
    __shared__ int cur[256];
    const int t = threadIdx.x;
    if (t < NB) cur[t] = bases[t * NBLK + blockIdx.x];
    __syncthreads();
    const int base = blockIdx.x * EPB;
    const int end  = min(base + EPB, E);
    for (int e = base + t; e < end; e += 256) {
        int dst = ei[E + e];
        int pos = atomicAdd(&cur[dst >> BSH], 1);
        uint2 rec;
        rec.x = (unsigned)ei[e] | ((unsigned)(dst & 255) << 24);  // src < 2^24
        rec.y = __builtin_bit_cast(unsigned, ea[e]);
        tmp[pos] = rec;
    }
}

// ---------- pass 4: counting sort within bucket -> sorted src_w, deg, offs ----------

__global__ __launch_bounds__(256) void bucket_sort(
    const uint2* __restrict__ tmp, const int* __restrict__ bucket_start,
    uint2* __restrict__ src_w, int* __restrict__ deg_i, int* __restrict__ offs,
    int N, int NB)
{
    __shared__ int cnt[256];
    __shared__ int sc[256];
    const int b = blockIdx.x;
    const int t = threadIdx.x;
    const int s0 = bucket_start[b];
    const int s1 = bucket_start[b + 1];
    cnt[t] = 0;
    __syncthreads();
    for (int i = s0 + t; i < s1; i += 256)
        atomicAdd(&cnt[tmp[i].x >> 24], 1);
    __syncthreads();
    const int orig = cnt[t];
    sc[t] = orig;
    __syncthreads();
    for (int off = 1; off < 256; off <<= 1) {
        int v = (t >= off) ? sc[t - off] : 0;
        __syncthreads();
        sc[t] += v;
        __syncthreads();
    }
    const int excl = sc[t] - orig;
    const int node = (b << BSH) + t;
    if (node < N) {
        deg_i[node] = orig;
        offs[node]  = s0 + excl;
    }
    cnt[t] = s0 + excl;    // becomes cursor
    __syncthreads();
    for (int i = s0 + t; i < s1; i += 256) {
        uint2 r = tmp[i];
        int pos = atomicAdd(&cnt[r.x >> 24], 1);
        r.x &= 0x00ffffffu;
        src_w[pos] = r;
    }
}

// ---------- per-node CSR aggregation (bf16 gather) -> out0 (bf16) ----------

__global__ __launch_bounds__(256) void node_agg(
    const float* __restrict__ x, const unsigned short* __restrict__ xb,
    const int* __restrict__ offs, const int* __restrict__ deg_i,
    const uint2* __restrict__ src_w, unsigned short* __restrict__ out0, int N)
{
    const int lane = threadIdx.x & 63;
    const int wid  = threadIdx.x >> 6;
    const int node = blockIdx.x * 4 + wid;
    if (node >= N) return;
    const int rs = offs[node];
    const int d  = deg_i[node];
    const int c  = lane * 2;
    float a0 = 0.f, a1 = 0.f;
    int j = 0;
    for (; j + 8 <= d; j += 8) {
        uint2 e[8];
        #pragma unroll
        for (int i = 0; i < 8; ++i) e[i] = src_w[rs + j + i];
        unsigned v[8];
        #pragma unroll
        for (int i = 0; i < 8; ++i)
            v[i] = *(const unsigned*)(xb + (long)e[i].x * C + c);
        #pragma unroll
        for (int i = 0; i < 8; ++i) {
            float w  = __builtin_bit_cast(float, e[i].y);
            a0 = fmaf(__builtin_bit_cast(float, v[i] << 16), w, a0);
            a1 = fmaf(__builtin_bit_cast(float, v[i] & 0xffff0000u), w, a1);
        }
    }
    for (; j < d; ++j) {
        uint2 e = src_w[rs + j];
        unsigned v = *(const unsigned*)(xb + (long)e.x * C + c);
        float w = __builtin_bit_cast(float, e.y);
        a0 = fmaf(__builtin_bit_cast(float, v << 16), w, a0);
        a1 = fmaf(__builtin_bit_cast(float, v & 0xffff0000u), w, a1);
    }
    float dd  = (d > 0) ? (float)d : 1.f;
    float inv = 1.f / dd;
    float2 xv = *(const float2*)(x + (long)node * C + c);
    float o0 = 0.5f * (xv.x + a0 * inv);
    float o1 = 0.5f * (xv.y + a1 * inv);
    unsigned pack = (unsigned)f2b(o0) | ((unsigned)f2b(o1) << 16);
    *(unsigned*)(out0 + (long)node * C + c) = pack;
}

// ---------- MFMA MLP: y = relu(out0 @ W1 + b1) @ W2 + b2 ----------

__global__ __launch_bounds__(256) void mlp_mfma(
    const unsigned short* __restrict__ out0,
    const unsigned short* __restrict__ W1p, const float* __restrict__ b1,
    const unsigned short* __restrict__ W2p, const float* __restrict__ b2,
    float* __restrict__ out, int N)
{
    __shared__ unsigned short hS[4][16][264];
    const int lane = threadIdx.x & 63;
    const int wid  = threadIdx.x >> 6;
    const int r16  = lane & 15;
    const int grp  = lane >> 4;
    const int nodeBase = blockIdx.x * MT + wid * 16;

    bf16x8 a1[4];
    {
        int arow = nodeBase + r16;
        if (arow >= N) arow = N - 1;
        const unsigned short* ar = out0 + (long)arow * C;
        #pragma unroll
        for (int kk = 0; kk < 4; ++kk) {
            s16x4 lo = *(const s16x4*)(ar + kk * 32 + 4 * grp);
            s16x4 hi = *(const s16x4*)(ar + kk * 32 + 16 + 4 * grp);
            bf16x8 a;
            a[0] = lo[0]; a[1] = lo[1]; a[2] = lo[2]; a[3] = lo[3];
            a[4] = hi[0]; a[5] = hi[1]; a[6] = hi[2]; a[7] = hi[3];
            a1[kk] = a;
        }
    }

    #pragma unroll 4
    for (int nt = 0; nt < 16; ++nt) {
        f32x4 acc = {0.f, 0.f, 0.f, 0.f};
        #pragma unroll
        for (int kk = 0; kk < 4; ++kk) {
            bf16x8 b = *(const bf16x8*)(W1p + (((nt * 4 + kk) * 64 + lane) << 3));
            acc = __builtin_amdgcn_mfma_f32_16x16x32_bf16(a1[kk], b, acc, 0, 0, 0);
        }
        float bias = b1[nt * 16 + r16];
        #pragma unroll
        for (int r = 0; r < 4; ++r) {
            float h = fmaxf(acc[r] + bias, 0.f);
            hS[wid][grp * 4 + r][nt * 16 + r16] = f2b(h);
        }
    }

    __syncthreads();

    bf16x8 a2[8];
    #pragma unroll
    for (int kk = 0; kk < 8; ++kk) {
        s16x4 lo = *(const s16x4*)&hS[wid][r16][kk * 32 + 4 * grp];
        s16x4 hi = *(const s16x4*)&hS[wid][r16][kk * 32 + 16 + 4 * grp];
        bf16x8 a;
        a[0] = lo[0]; a[1] = lo[1]; a[2] = lo[2]; a[3] = lo[3];
        a[4] = hi[0]; a[5] = hi[1]; a[6] = hi[2]; a[7] = hi[3];
        a2[kk] = a;
    }

    #pragma unroll 2
    for (int nt = 0; nt < 8; ++nt) {
        f32x4 acc = {0.f, 0.f, 0.f, 0.f};
        #pragma unroll
        for (int kk = 0; kk < 8; ++kk) {
            bf16x8 b = *(const bf16x8*)(W2p + (((nt * 8 + kk) * 64 + lane) << 3));
            acc = __builtin_amdgcn_mfma_f32_16x16x32_bf16(a2[kk], b, acc, 0, 0, 0);
        }
        float bias = b2[nt * 16 + r16];
        #pragma unroll
        for (int r = 0; r < 4; ++r) {
            int node = nodeBase + grp * 4 + r;
            if (node < N) out[(long)node * C + nt * 16 + r16] = acc[r] + bias;
        }
    }
}

extern "C" void kernel_launch(void* const* d_in, const int* in_sizes, int n_in,
                              void* d_out, int out_size, void* d_ws, size_t ws_size,
                              hipStream_t stream) {
    const float* x  = (const float*)d_in[0];
    const int*   ei = (const int*)d_in[1];
    const float* ea = (const float*)d_in[2];
    const float* W1 = (const float*)d_in[3];
    const float* b1 = (const float*)d_in[4];
    const float* W2 = (const float*)d_in[5];
    const float* b2 = (const float*)d_in[6];
    float* out = (float*)d_out;
    const int N = in_sizes[0] / C;
    const int E = in_sizes[2];

    const int NB   = (N + 255) >> BSH;           // buckets (<=256 for N<=65536)
    const int NBLK = (E + EPB - 1) / EPB;        // edge blocks

    // workspace layout (16B-aligned chunks)
    char* p = (char*)d_ws;
    auto alloc = [&](size_t bytes) { char* q = p; p += (bytes + 15) & ~(size_t)15; return q; };
    int* deg_i        = (int*)alloc((size_t)N * 4);
    int* offs         = (int*)alloc((size_t)N * 4);
    int* counts       = (int*)alloc((size_t)NB * NBLK * 4);   // becomes bases
    int* bucket_start = (int*)alloc((size_t)(NB + 1) * 4);
    uint2* src_w      = (uint2*)alloc((size_t)E * 8);
    // out0 region doubles as tmp (tmp dead before node_agg writes out0)
    char* out0_raw    = alloc((((size_t)N * C * 2) > ((size_t)E * 8)) ? ((size_t)N * C * 2) : ((size_t)E * 8));
    unsigned short* out0 = (unsigned short*)out0_raw;
    uint2* tmp        = (uint2*)out0_raw;
    unsigned short* W1p = (unsigned short*)alloc((size_t)C * HID * 2);
    unsigned short* W2p = (unsigned short*)alloc((size_t)HID * C * 2);
    unsigned short* xb  = (unsigned short*)alloc((size_t)N * C * 2);

    const long total4 = ((long)N * C) / 4;

    convert_x<<<(int)((total4 + 255) / 256), 256, 0, stream>>>(x, xb, total4);
    convert_w<<<(C * HID + 255) / 256, 256, 0, stream>>>(W1, W2, W1p, W2p);
    bucket_count<<<NBLK, 256, 0, stream>>>(ei, counts, E, NB, NBLK);
    bucket_scan<<<1, 256, 0, stream>>>(counts, bucket_start, NB, NBLK);
    bucket_scatter<<<NBLK, 256, 0, stream>>>(ei, ea, counts, tmp, E, NB, NBLK);
    bucket_sort<<<NB, 256, 0, stream>>>(tmp, bucket_start, src_w, deg_i, offs, N, NB);
    node_agg<<<(N + 3) / 4, 256, 0, stream>>>(x, xb, offs, deg_i, src_w, out0, N);
    mlp_mfma<<<(N + MT - 1) / MT, 256, 0, stream>>>(out0, W1p, b1, W2p, b2, out, N);
}

// Round 6
// 120.196 us; speedup vs baseline: 1.5111x; 1.5111x over previous
//
#include <hip/hip_runtime.h>

#define C 128
#define HID 256
#define MT 64     // nodes per block in mlp_mfma
#define EPB 2048  // edges per block in bucket passes
#define BSH 8     // nodes per bucket = 256

typedef __attribute__((ext_vector_type(8))) short bf16x8;
typedef __attribute__((ext_vector_type(4))) short s16x4;
typedef __attribute__((ext_vector_type(4))) float f32x4;

__device__ inline unsigned short f2b(float f) {
    unsigned u = __builtin_bit_cast(unsigned, f);
    unsigned r = u + 0x7fffu + ((u >> 16) & 1u);
    return (unsigned short)(r >> 16);
}

// ---------- x -> bf16 copy ----------

__global__ __launch_bounds__(256) void convert_x(
    const float* __restrict__ x, unsigned short* __restrict__ xb, long total4)
{
    long i = (long)blockIdx.x * 256 + threadIdx.x;
    if (i < total4) {
        float4 v = *(const float4*)(x + i * 4);
        ushort4 o;
        o.x = f2b(v.x); o.y = f2b(v.y); o.z = f2b(v.z); o.w = f2b(v.w);
        *(ushort4*)(xb + i * 4) = o;
    }
}

// ---------- weight convert + permute into MFMA B-fragment order ----------
// lane l, elem j holds B[k][n]: n = nt*16+(l&15), k = kk*32+16*(j>>2)+4*(l>>4)+(j&3)

__global__ __launch_bounds__(256) void convert_w(
    const float* __restrict__ W1, const float* __restrict__ W2,
    unsigned short* __restrict__ W1p, unsigned short* __restrict__ W2p)
{
    int t = blockIdx.x * 256 + threadIdx.x;
    if (t < C * HID) {
        {
            int j = t & 7, l = (t >> 3) & 63, kk = (t >> 9) & 3, nt = t >> 11;
            int n = nt * 16 + (l & 15);
            int k = kk * 32 + 16 * (j >> 2) + 4 * (l >> 4) + (j & 3);
            W1p[t] = f2b(W1[k * HID + n]);
        }
        {
            int j = t & 7, l = (t >> 3) & 63, kk = (t >> 9) & 7, nt = t >> 12;
            int n = nt * 16 + (l & 15);
            int k = kk * 32 + 16 * (j >> 2) + 4 * (l >> 4) + (j & 3);
            W2p[t] = f2b(W2[k * C + n]);
        }
    }
}

// ---------- bucket sort pass 1: per-block histogram over buckets ----------

__global__ __launch_bounds__(256) void bucket_count(
    const int* __restrict__ ei, int* __restrict__ counts, int E, int NB, int NBLK)
{
    __shared__ int bins[256];   // NB <= 256 (N <= 65536)
    const int t = threadIdx.x;
    bins[t] = 0;
    __syncthreads();
    const int base = blockIdx.x * EPB;
    const int end  = min(base + EPB, E);
    for (int e = base + t; e < end; e += 256)
        atomicAdd(&bins[ei[E + e] >> BSH], 1);
    __syncthreads();
    if (t < NB) counts[t * NBLK + blockIdx.x] = bins[t];
}

// ---------- pass 2a: per-bucket totals (parallel over buckets) ----------

__global__ __launch_bounds__(256) void bucket_tot(
    const int* __restrict__ counts, int* __restrict__ btot, int NBLK)
{
    __shared__ int s[256];
    const int b = blockIdx.x;
    const int t = threadIdx.x;
    int sum = 0;
    for (int i = t; i < NBLK; i += 256) sum += counts[b * NBLK + i];
    s[t] = sum;
    __syncthreads();
    for (int off = 128; off > 0; off >>= 1) {
        if (t < off) s[t] += s[t + off];
        __syncthreads();
    }
    if (t == 0) btot[b] = s[0];
}

// ---------- pass 2b: scan bucket totals -> bucket_start (1 block, NB<=256) ----------

__global__ __launch_bounds__(256) void bucket_start_k(
    const int* __restrict__ btot, int* __restrict__ bucket_start, int NB)
{
    __shared__ int s[256];
    const int t = threadIdx.x;
    int v = (t < NB) ? btot[t] : 0;
    s[t] = v;
    __syncthreads();
    for (int off = 1; off < 256; off <<= 1) {
        int u = (t >= off) ? s[t - off] : 0;
        __syncthreads();
        s[t] += u;
        __syncthreads();
    }
    if (t < NB) bucket_start[t] = s[t] - v;
    if (t == NB - 1) bucket_start[NB] = s[t];
}

// ---------- pass 2c: per-(bucket,block) bases (parallel over buckets) ----------

__global__ __launch_bounds__(256) void bucket_bases(
    int* __restrict__ counts, const int* __restrict__ bucket_start, int NBLK)
{
    __shared__ int s[256];
    __shared__ int carry_s;
    const int b = blockIdx.x;
    const int t = threadIdx.x;
    if (t == 0) carry_s = bucket_start[b];
    __syncthreads();
    for (int base = 0; base < NBLK; base += 256) {
        const int i = base + t;
        int v = (i < NBLK) ? counts[b * NBLK + i] : 0;
        s[t] = v;
        __syncthreads();
        for (int off = 1; off < 256; off <<= 1) {
            int u = (t >= off) ? s[t - off] : 0;
            __syncthreads();
            s[t] += u;
            __syncthreads();
        }
        const int c = carry_s;
        if (i < NBLK) counts[b * NBLK + i] = c + s[t] - v;
        __syncthreads();
        if (t == 0) carry_s = c + s[255];
        __syncthreads();
    }
}

// ---------- pass 3: scatter edges into bucket-partitioned tmp ----------

__global__ __launch_bounds__(256) void bucket_scatter(
    const int* __restrict__ ei, const float* __restrict__ ea,
    const int* __restrict__ bases, uint2* __restrict__ tmp,
    int E, int NB, int NBLK)
{
    __shared__ int cur[256];
    const int t = threadIdx.x;
    if (t < NB) cur[t] = bases[t * NBLK + blockIdx.x];
    __syncthreads();
    const int base = blockIdx.x * EPB;
    const int end  = min(base + EPB, E);
    for (int e = base + t; e < end; e += 256) {
        int dst = ei[E + e];
        int pos = atomicAdd(&cur[dst >> BSH], 1);
        uint2 rec;
        rec.x = (unsigned)ei[e] | ((unsigned)(dst & 255) << 24);  // src < 2^24
        rec.y = __builtin_bit_cast(unsigned, ea[e]);
        tmp[pos] = rec;
    }
}

// ---------- pass 4: counting sort within bucket -> sorted src_w, deg, offs ----------

__global__ __launch_bounds__(256) void bucket_sort(
    const uint2* __restrict__ tmp, const int* __restrict__ bucket_start,
    uint2* __restrict__ src_w, int* __restrict__ deg_i, int* __restrict__ offs,
    int N, int NB)
{
    __shared__ int cnt[256];
    __shared__ int sc[256];
    const int b = blockIdx.x;
    const int t = threadIdx.x;
    const int s0 = bucket_start[b];
    const int s1 = bucket_start[b + 1];
    cnt[t] = 0;
    __syncthreads();
    for (int i = s0 + t; i < s1; i += 256)
        atomicAdd(&cnt[tmp[i].x >> 24], 1);
    __syncthreads();
    const int orig = cnt[t];
    sc[t] = orig;
    __syncthreads();
    for (int off = 1; off < 256; off <<= 1) {
        int v = (t >= off) ? sc[t - off] : 0;
        __syncthreads();
        sc[t] += v;
        __syncthreads();
    }
    const int excl = sc[t] - orig;
    const int node = (b << BSH) + t;
    if (node < N) {
        deg_i[node] = orig;
        offs[node]  = s0 + excl;
    }
    cnt[t] = s0 + excl;    // becomes cursor
    __syncthreads();
    for (int i = s0 + t; i < s1; i += 256) {
        uint2 r = tmp[i];
        int pos = atomicAdd(&cnt[r.x >> 24], 1);
        r.x &= 0x00ffffffu;
        src_w[pos] = r;
    }
}

// ---------- per-node CSR aggregation (bf16 gather) -> out0 (bf16) ----------

__global__ __launch_bounds__(256) void node_agg(
    const float* __restrict__ x, const unsigned short* __restrict__ xb,
    const int* __restrict__ offs, const int* __restrict__ deg_i,
    const uint2* __restrict__ src_w, unsigned short* __restrict__ out0, int N)
{
    const int lane = threadIdx.x & 63;
    const int wid  = threadIdx.x >> 6;
    const int node = blockIdx.x * 4 + wid;
    if (node >= N) return;
    const int rs = offs[node];
    const int d  = deg_i[node];
    const int c  = lane * 2;
    float a0 = 0.f, a1 = 0.f;
    int j = 0;
    for (; j + 8 <= d; j += 8) {
        uint2 e[8];
        #pragma unroll
        for (int i = 0; i < 8; ++i) e[i] = src_w[rs + j + i];
        unsigned v[8];
        #pragma unroll
        for (int i = 0; i < 8; ++i)
            v[i] = *(const unsigned*)(xb + (long)e[i].x * C + c);
        #pragma unroll
        for (int i = 0; i < 8; ++i) {
            float w  = __builtin_bit_cast(float, e[i].y);
            a0 = fmaf(__builtin_bit_cast(float, v[i] << 16), w, a0);
            a1 = fmaf(__builtin_bit_cast(float, v[i] & 0xffff0000u), w, a1);
        }
    }
    for (; j < d; ++j) {
        uint2 e = src_w[rs + j];
        unsigned v = *(const unsigned*)(xb + (long)e.x * C + c);
        float w = __builtin_bit_cast(float, e.y);
        a0 = fmaf(__builtin_bit_cast(float, v << 16), w, a0);
        a1 = fmaf(__builtin_bit_cast(float, v & 0xffff0000u), w, a1);
    }
    float dd  = (d > 0) ? (float)d : 1.f;
    float inv = 1.f / dd;
    float2 xv = *(const float2*)(x + (long)node * C + c);
    float o0 = 0.5f * (xv.x + a0 * inv);
    float o1 = 0.5f * (xv.y + a1 * inv);
    unsigned pack = (unsigned)f2b(o0) | ((unsigned)f2b(o1) << 16);
    *(unsigned*)(out0 + (long)node * C + c) = pack;
}

// ---------- MFMA MLP: y = relu(out0 @ W1 + b1) @ W2 + b2 ----------

__global__ __launch_bounds__(256) void mlp_mfma(
    const unsigned short* __restrict__ out0,
    const unsigned short* __restrict__ W1p, const float* __restrict__ b1,
    const unsigned short* __restrict__ W2p, const float* __restrict__ b2,
    float* __restrict__ out, int N)
{
    __shared__ unsigned short hS[4][16][264];
    const int lane = threadIdx.x & 63;
    const int wid  = threadIdx.x >> 6;
    const int r16  = lane & 15;
    const int grp  = lane >> 4;
    const int nodeBase = blockIdx.x * MT + wid * 16;

    bf16x8 a1[4];
    {
        int arow = nodeBase + r16;
        if (arow >= N) arow = N - 1;
        const unsigned short* ar = out0 + (long)arow * C;
        #pragma unroll
        for (int kk = 0; kk < 4; ++kk) {
            s16x4 lo = *(const s16x4*)(ar + kk * 32 + 4 * grp);
            s16x4 hi = *(const s16x4*)(ar + kk * 32 + 16 + 4 * grp);
            bf16x8 a;
            a[0] = lo[0]; a[1] = lo[1]; a[2] = lo[2]; a[3] = lo[3];
            a[4] = hi[0]; a[5] = hi[1]; a[6] = hi[2]; a[7] = hi[3];
            a1[kk] = a;
        }
    }

    #pragma unroll 4
    for (int nt = 0; nt < 16; ++nt) {
        f32x4 acc = {0.f, 0.f, 0.f, 0.f};
        #pragma unroll
        for (int kk = 0; kk < 4; ++kk) {
            bf16x8 b = *(const bf16x8*)(W1p + (((nt * 4 + kk) * 64 + lane) << 3));
            acc = __builtin_amdgcn_mfma_f32_16x16x32_bf16(a1[kk], b, acc, 0, 0, 0);
        }
        float bias = b1[nt * 16 + r16];
        #pragma unroll
        for (int r = 0; r < 4; ++r) {
            float h = fmaxf(acc[r] + bias, 0.f);
            hS[wid][grp * 4 + r][nt * 16 + r16] = f2b(h);
        }
    }

    __syncthreads();

    bf16x8 a2[8];
    #pragma unroll
    for (int kk = 0; kk < 8; ++kk) {
        s16x4 lo = *(const s16x4*)&hS[wid][r16][kk * 32 + 4 * grp];
        s16x4 hi = *(const s16x4*)&hS[wid][r16][kk * 32 + 16 + 4 * grp];
        bf16x8 a;
        a[0] = lo[0]; a[1] = lo[1]; a[2] = lo[2]; a[3] = lo[3];
        a[4] = hi[0]; a[5] = hi[1]; a[6] = hi[2]; a[7] = hi[3];
        a2[kk] = a;
    }

    #pragma unroll 2
    for (int nt = 0; nt < 8; ++nt) {
        f32x4 acc = {0.f, 0.f, 0.f, 0.f};
        #pragma unroll
        for (int kk = 0; kk < 8; ++kk) {
            bf16x8 b = *(const bf16x8*)(W2p + (((nt * 8 + kk) * 64 + lane) << 3));
            acc = __builtin_amdgcn_mfma_f32_16x16x32_bf16(a2[kk], b, acc, 0, 0, 0);
        }
        float bias = b2[nt * 16 + r16];
        #pragma unroll
        for (int r = 0; r < 4; ++r) {
            int node = nodeBase + grp * 4 + r;
            if (node < N) out[(long)node * C + nt * 16 + r16] = acc[r] + bias;
        }
    }
}

extern "C" void kernel_launch(void* const* d_in, const int* in_sizes, int n_in,
                              void* d_out, int out_size, void* d_ws, size_t ws_size,
                              hipStream_t stream) {
    const float* x  = (const float*)d_in[0];
    const int*   ei = (const int*)d_in[1];
    const float* ea = (const float*)d_in[2];
    const float* W1 = (const float*)d_in[3];
    const float* b1 = (const float*)d_in[4];
    const float* W2 = (const float*)d_in[5];
    const float* b2 = (const float*)d_in[6];
    float* out = (float*)d_out;
    const int N = in_sizes[0] / C;
    const int E = in_sizes[2];

    const int NB   = (N + 255) >> BSH;           // buckets (<=256 for N<=65536)
    const int NBLK = (E + EPB - 1) / EPB;        // edge blocks

    // workspace layout (16B-aligned chunks)
    char* p = (char*)d_ws;
    auto alloc = [&](size_t bytes) { char* q = p; p += (bytes + 15) & ~(size_t)15; return q; };
    int* deg_i        = (int*)alloc((size_t)N * 4);
    int* offs         = (int*)alloc((size_t)N * 4);
    int* counts       = (int*)alloc((size_t)NB * NBLK * 4);   // becomes bases
    int* btot         = (int*)alloc((size_t)NB * 4);
    int* bucket_start = (int*)alloc((size_t)(NB + 1) * 4);
    uint2* src_w      = (uint2*)alloc((size_t)E * 8);
    // out0 region doubles as tmp (tmp dead before node_agg writes out0)
    char* out0_raw    = alloc((((size_t)N * C * 2) > ((size_t)E * 8)) ? ((size_t)N * C * 2) : ((size_t)E * 8));
    unsigned short* out0 = (unsigned short*)out0_raw;
    uint2* tmp        = (uint2*)out0_raw;
    unsigned short* W1p = (unsigned short*)alloc((size_t)C * HID * 2);
    unsigned short* W2p = (unsigned short*)alloc((size_t)HID * C * 2);
    unsigned short* xb  = (unsigned short*)alloc((size_t)N * C * 2);

    const long total4 = ((long)N * C) / 4;

    convert_x<<<(int)((total4 + 255) / 256), 256, 0, stream>>>(x, xb, total4);
    convert_w<<<(C * HID + 255) / 256, 256, 0, stream>>>(W1, W2, W1p, W2p);
    bucket_count<<<NBLK, 256, 0, stream>>>(ei, counts, E, NB, NBLK);
    bucket_tot<<<NB, 256, 0, stream>>>(counts, btot, NBLK);
    bucket_start_k<<<1, 256, 0, stream>>>(btot, bucket_start, NB);
    bucket_bases<<<NB, 256, 0, stream>>>(counts, bucket_start, NBLK);
    bucket_scatter<<<NBLK, 256, 0, stream>>>(ei, ea, counts, tmp, E, NB, NBLK);
    bucket_sort<<<NB, 256, 0, stream>>>(tmp, bucket_start, src_w, deg_i, offs, N, NB);
    node_agg<<<(N + 3) / 4, 256, 0, stream>>>(x, xb, offs, deg_i, src_w, out0, N);
    mlp_mfma<<<(N + MT - 1) / MT, 256, 0, stream>>>(out0, W1p, b1, W2p, b2, out, N);
}